// Round 9
// baseline (194.635 us; speedup 1.0000x reference)
//
#include <hip/hip_runtime.h>
#include <hip/hip_bf16.h>
#include <stdint.h>

typedef unsigned short ushort_t;
typedef short v8s __attribute__((ext_vector_type(8)));
typedef float f32x4 __attribute__((ext_vector_type(4)));
typedef float f32x16 __attribute__((ext_vector_type(16)));

#define MFMA16(a, b, c) __builtin_amdgcn_mfma_f32_16x16x32_bf16(a, b, c, 0, 0, 0)
#define MFMA32(a, b, c) __builtin_amdgcn_mfma_f32_32x32x16_bf16(a, b, c, 0, 0, 0)

__device__ __forceinline__ ushort_t f2bf(float f) {
    union { __hip_bfloat16 b; ushort_t u; } c;
    c.b = __float2bfloat16(f);
    return c.u;
}

__device__ __forceinline__ unsigned f2bf2(float a, float b) {
    union { __hip_bfloat162 b2; unsigned u; } c;
    c.b2 = __float22bfloat162_rn(make_float2(a, b));
    return c.u;
}

// ---------------------------------------------------------------------------
// Kernel 1: transpose W [2048][128] f32 -> WT [384][2048] bf16 (q|k|v rows)
// ---------------------------------------------------------------------------
__global__ void transpose_w(const float* __restrict__ Wq, const float* __restrict__ Wk,
                            const float* __restrict__ Wv, ushort_t* __restrict__ WT) {
    __shared__ float tile[64][132];
    int bid = blockIdx.x;            // 96 = 3 weights x 32 k-blocks
    int w = bid >> 5;
    int k0 = (bid & 31) << 6;
    const float* W = (w == 0) ? Wq : ((w == 1) ? Wk : Wv);
    int tid = threadIdx.x;
    #pragma unroll
    for (int i = 0; i < 8; i++) {
        int row = i * 8 + (tid >> 5);
        int col = (tid & 31) * 4;
        float4 v = *(const float4*)(W + (size_t)(k0 + row) * 128 + col);
        tile[row][col] = v.x; tile[row][col + 1] = v.y;
        tile[row][col + 2] = v.z; tile[row][col + 3] = v.w;
    }
    __syncthreads();
    int n = tid >> 1, kh = (tid & 1) * 32;
    ushort_t* dst = WT + ((size_t)(w * 128 + n)) * 2048 + k0 + kh;
    #pragma unroll
    for (int j = 0; j < 32; j += 4) {
        union { ushort_t u[4]; uint2 v2; } pk;
        #pragma unroll
        for (int e = 0; e < 4; e++) pk.u[e] = f2bf(tile[kh + j + e][n]);
        *(uint2*)(dst + j) = pk.v2;
    }
}

// ---------------------------------------------------------------------------
// Kernel 2: fused QKV projection v9 — attn-style: ZERO LDS, ZERO barriers,
// 32x32 MFMA, pure register dataflow, compiler-scheduled.
// Wave = 32m x 96n (acc[3] f32x16 = 48 VGPR), BK=64, 32 iters, 12 MFMA32/iter.
//   A (x): lane lo = x-row, per ks 32B f32 (2 f32x4) -> cvt_pk -> v8s frag.
//          1-ahead ping-pong reg sets (x is L3-resident, ~500cy).
//   B (WT): lane lo = w-col, 16B v8s JIT from L2/L1 (~300cy, hidden by MFMA).
// Block = 4 waves STACKED IN M (same 96 cols, ~lockstep K) -> B hits L1
// (12 KB/iter working set). Grid 512 = 8 xcd x 16 mtl x 4 nq; nq-siblings
// same XCD (bids differ by 8) -> x tile (1 MB) shared via XCD L2.
// D-frag (m74): lane lo = output col n, rows m = (r&3)+8*(r>>2)+4*hi.
// Blocked output layouts (per batch 524288 elems):
//   q_blk/k_blk: (t>>5)*4096 + (d>>4)*512 + ((d>>3)&1)*256 + (t&31)*8 + (d&7)
//   v_blk:       (t>>4)*2048 + (d>>5)*512 + ((t>>3)&1)*256 + (d&31)*8 + (t&7)
// ---------------------------------------------------------------------------
#define PJ_XLOAD(S, IT)                                                       \
    {                                                                         \
        _Pragma("unroll")                                                     \
        for (int ks = 0; ks < 4; ks++) {                                      \
            S[2 * ks]     = *(const f32x4*)(xrow + (size_t)(IT) * 256 + ks * 64);      \
            S[2 * ks + 1] = *(const f32x4*)(xrow + (size_t)(IT) * 256 + ks * 64 + 16); \
        }                                                                     \
    }

#define PJ_STEP(CVT, LOADSET, IT, DOLOAD)                                     \
    {                                                                         \
        if (DOLOAD) PJ_XLOAD(LOADSET, (IT) + 1);                              \
        v8s af[4];                                                            \
        _Pragma("unroll")                                                     \
        for (int ks = 0; ks < 4; ks++) {                                      \
            union { unsigned u[4]; v8s v; } pk;                               \
            pk.u[0] = f2bf2(CVT[2 * ks][0], CVT[2 * ks][1]);                  \
            pk.u[1] = f2bf2(CVT[2 * ks][2], CVT[2 * ks][3]);                  \
            pk.u[2] = f2bf2(CVT[2 * ks + 1][0], CVT[2 * ks + 1][1]);          \
            pk.u[3] = f2bf2(CVT[2 * ks + 1][2], CVT[2 * ks + 1][3]);          \
            af[ks] = pk.v;                                                    \
        }                                                                     \
        v8s bf[3][4];                                                         \
        _Pragma("unroll")                                                     \
        for (int nt = 0; nt < 3; nt++)                                        \
            _Pragma("unroll")                                                 \
            for (int ks = 0; ks < 4; ks++)                                    \
                bf[nt][ks] = *(const v8s*)(wrow[nt] + (size_t)(IT) * 128 + ks * 32); \
        __builtin_amdgcn_s_setprio(1);                                        \
        _Pragma("unroll")                                                     \
        for (int ks = 0; ks < 4; ks++)                                        \
            _Pragma("unroll")                                                 \
            for (int nt = 0; nt < 3; nt++)                                    \
                acc[nt] = MFMA32(af[ks], bf[nt][ks], acc[nt]);                \
        __builtin_amdgcn_s_setprio(0);                                        \
    }

__device__ __forceinline__ f32x16 pzero16() {
    f32x16 z;
    #pragma unroll
    for (int i = 0; i < 16; i++) z[i] = 0.f;
    return z;
}

__launch_bounds__(256, 2)
__global__ void proj_kernel(const float* __restrict__ x, const ushort_t* __restrict__ WT,
                            ushort_t* __restrict__ q, ushort_t* __restrict__ kb,
                            ushort_t* __restrict__ vb) {
    int bid = blockIdx.x;
    int xcd = bid & 7, nq = (bid >> 3) & 3, mtl = bid >> 5;
    int mtile = xcd * 16 + mtl;
    size_t m0 = (size_t)mtile * 128;
    int c0 = nq * 96;
    int tid = threadIdx.x, lane = tid & 63, wid = tid >> 6;
    int hi = lane >> 5, lo = lane & 31;

    f32x16 acc[3];
    #pragma unroll
    for (int nt = 0; nt < 3; nt++) acc[nt] = pzero16();

    // A: lane reads its own x row (wave = rows wid*32..+31), hi = k-half
    const char* xrow = (const char*)x + (m0 + (size_t)(wid * 32 + lo)) * 8192 + hi * 32;
    // B: lane lo reads WT row = its output column; hi = k-half
    const char* wrow[3];
    #pragma unroll
    for (int nt = 0; nt < 3; nt++)
        wrow[nt] = (const char*)WT + (size_t)(c0 + nt * 32 + lo) * 4096 + hi * 16;

    f32x4 xa[8], xb[8];
    PJ_XLOAD(xa, 0);

    for (int it = 0; it < 32; it += 2) {
        PJ_STEP(xa, xb, it, 1);
        PJ_STEP(xb, xa, it + 1, (it < 30));
    }

    // epilogue: value[nt][r] = out[t][d], t = m0 + wid*32 + (r&3)+8*(r>>2)+4*hi,
    // d = c0 + nt*32 + lo
    int t0 = (int)(m0 & 4095) + wid * 32 + 4 * hi;
    size_t base = (m0 >> 12) * 524288;
    #pragma unroll
    for (int nt = 0; nt < 3; nt++) {
        int d = c0 + nt * 32 + lo;
        int w = d >> 7, dd = d & 127;
        if (w < 2) {
            ushort_t* dst = (w == 0) ? q : kb;
            size_t cbase = base + (size_t)((t0 & ~31) >> 5) * 4096
                         + (size_t)(dd >> 4) * 512 + ((dd >> 3) & 1) * 256 + (dd & 7);
            #pragma unroll
            for (int r = 0; r < 16; r++) {
                int crow = (t0 & 31) + (r & 3) + 8 * (r >> 2);
                dst[cbase + crow * 8] = f2bf(acc[nt][r]);
            }
        } else {
            size_t vb0 = base + (size_t)(dd >> 5) * 512 + (dd & 31) * 8;
            #pragma unroll
            for (int r = 0; r < 16; r++) {
                int t = t0 + (r & 3) + 8 * (r >> 2);
                vb[vb0 + (size_t)(t >> 4) * 2048 + ((t >> 3) & 1) * 256 + (t & 7)]
                    = f2bf(acc[nt][r]);
            }
        }
    }
}

// ---------------------------------------------------------------------------
// Kernel 3: causal flash attention (UNCHANGED — ~19 µs, ~900 TF effective).
// 32x32 MFMA, swapped QK^T (S^T = K·Q^T), O^T = V^T·P^T. 512 blocks x 4
// waves; waves split KV tiles mod 4, merge partials via LDS at the end.
// ---------------------------------------------------------------------------
__device__ __forceinline__ f32x16 zero16() {
    f32x16 z;
    #pragma unroll
    for (int i = 0; i < 16; i++) z[i] = 0.f;
    return z;
}

#define ATT_PVC(SV, BASE, VC, CNEXT)                                          \
    {                                                                         \
        unsigned a0 = f2bf2(SV[(BASE) + 0], SV[(BASE) + 1]);                  \
        unsigned a1 = f2bf2(SV[(BASE) + 2], SV[(BASE) + 3]);                  \
        unsigned b0 = f2bf2(SV[(BASE) + 4], SV[(BASE) + 5]);                  \
        unsigned b1 = f2bf2(SV[(BASE) + 6], SV[(BASE) + 7]);                  \
        unsigned snd0 = hi ? a0 : b0, snd1 = hi ? a1 : b1;                    \
        unsigned rcv0 = (unsigned)__shfl_xor((int)snd0, 32);                  \
        unsigned rcv1 = (unsigned)__shfl_xor((int)snd1, 32);                  \
        union { unsigned u[4]; v8s v; } pf;                                   \
        pf.u[0] = hi ? rcv0 : a0;                                             \
        pf.u[1] = hi ? rcv1 : a1;                                             \
        pf.u[2] = hi ? b0 : rcv0;                                             \
        pf.u[3] = hi ? b1 : rcv1;                                             \
        __builtin_amdgcn_s_setprio(1);                                        \
        _Pragma("unroll")                                                     \
        for (int dt = 0; dt < 4; dt++)                                        \
            accO[dt] = MFMA32(VC[dt], pf.v, accO[dt]);                        \
        __builtin_amdgcn_s_setprio(0);                                        \
        if ((CNEXT) >= 0) {                                                   \
            _Pragma("unroll")                                                 \
            for (int dt = 0; dt < 4; dt++)                                    \
                VC[dt] = *(const v8s*)(vg + (CNEXT) * 2048 + dt * 512);       \
        }                                                                     \
    }

__launch_bounds__(256, 2)
__global__ void attn_kernel(const ushort_t* __restrict__ q, const ushort_t* __restrict__ kb,
                            const ushort_t* __restrict__ vb, float* __restrict__ out) {
    __shared__ float obuf[4][4][16][64];   // [srcwave][dt][r][lane]  64 KB
    __shared__ float stat[2][4][64];       // m, l per wave per lane

    int bid = blockIdx.x;
    int xcd = bid & 7, rk = bid >> 3;
    int b = xcd >> 1;                       // batch pinned to XCD pair
    int g = rk * 2 + (xcd & 1);             // 0..127
    int qt = (g & 1) ? (g >> 1) : (127 - (g >> 1));   // alternate long/short
    int qt0 = qt * 32;
    int tid = threadIdx.x, lane = tid & 63, wid = tid >> 6;
    int hi = lane >> 5, lo = lane & 31;
    size_t bb = (size_t)b * 524288;
    int nt = (qt >> 1) + 1;
    const float cexp = 0.08838834764831845f * 1.4426950408889634f;  // scale*log2e

    // Q fragments (B-operand): lane holds Q[qt0+lo][ks*16+hi*8+j]
    v8s qf[8];
    {
        const ushort_t* qg = q + bb + (size_t)qt * 4096 + (size_t)lane * 8;
        #pragma unroll
        for (int ks = 0; ks < 8; ks++) qf[ks] = *(const v8s*)(qg + ks * 512);
    }

    f32x16 accO[4];
    #pragma unroll
    for (int dt = 0; dt < 4; dt++) accO[dt] = zero16();
    float mrun = -1e30f, lrun = 0.f;

    for (int t = wid; t < nt; t += 4) {
        const ushort_t* kg = kb + bb + (size_t)t * 8192 + (size_t)lane * 8;
        const ushort_t* vg = vb + bb + (size_t)t * 8192 + (size_t)lane * 8;

        // S^T = K·Q^T : two 32-kv subtiles, K-loop over d (8 steps of 16)
        f32x16 s0 = zero16(), s1 = zero16();
        __builtin_amdgcn_s_setprio(1);
        #pragma unroll
        for (int ks = 0; ks < 8; ks++) {
            v8s kf = *(const v8s*)(kg + ks * 512);
            s0 = MFMA32(kf, qf[ks], s0);
        }
        #pragma unroll
        for (int ks = 0; ks < 8; ks++) {
            v8s kf = *(const v8s*)(kg + 4096 + ks * 512);
            s1 = MFMA32(kf, qf[ks], s1);
        }
        __builtin_amdgcn_s_setprio(0);

        // V-frag rolling pair: c=0 and c=1 issued here, latency hidden by
        // the mask + softmax VALU below.
        v8s vA[4], vB[4];
        #pragma unroll
        for (int dt = 0; dt < 4; dt++) vA[dt] = *(const v8s*)(vg + dt * 512);
        #pragma unroll
        for (int dt = 0; dt < 4; dt++) vB[dt] = *(const v8s*)(vg + 2048 + dt * 512);

        // causal mask (diagonal tile only); S^T row index kv=(r&3)+8*(r>>2)+4*hi
        if (t == nt - 1) {
            int qrow = qt0 + lo;
            #pragma unroll
            for (int r = 0; r < 16; r++) {
                int kvb = t * 64 + (r & 3) + 8 * (r >> 2) + 4 * hi;
                if (kvb > qrow) s0[r] = -1e30f;
                if (kvb + 32 > qrow) s1[r] = -1e30f;
            }
        }

        // online softmax: lane owns q-row lo; only cross-lane op is xor-32
        float mx = s0[0];
        #pragma unroll
        for (int r = 1; r < 16; r++) mx = fmaxf(mx, s0[r]);
        #pragma unroll
        for (int r = 0; r < 16; r++) mx = fmaxf(mx, s1[r]);
        mx = fmaxf(mx, __shfl_xor(mx, 32));

        if (__any(mx > mrun + 62.7f)) {     // defer-max: skip rescale if growth < 8/cexp
            float mnew = fmaxf(mrun, mx);
            float fr = exp2f((mrun - mnew) * cexp);
            lrun *= fr;
            #pragma unroll
            for (int dt = 0; dt < 4; dt++)
                #pragma unroll
                for (int r = 0; r < 16; r++) accO[dt][r] *= fr;
            mrun = mnew;
        }
        float mc = mrun * cexp;
        float rs = 0.f;
        #pragma unroll
        for (int r = 0; r < 16; r++) { s0[r] = exp2f(fmaf(s0[r], cexp, -mc)); rs += s0[r]; }
        #pragma unroll
        for (int r = 0; r < 16; r++) { s1[r] = exp2f(fmaf(s1[r], cexp, -mc)); rs += s1[r]; }
        rs += __shfl_xor(rs, 32);
        lrun += rs;

        // PV: O^T += V^T·P^T ; P-frag assembled in-loop (1 shfl pair / chunk),
        // V-frags prefetched 2 chunks ahead into the just-consumed set.
        ATT_PVC(s0, 0, vA, 2);
        ATT_PVC(s0, 8, vB, 3);
        ATT_PVC(s1, 0, vA, -1);
        ATT_PVC(s1, 8, vB, -1);
    }

    // ---- merge the 4 waves' partial (m, l, O^T) states ----
    #pragma unroll
    for (int dt = 0; dt < 4; dt++)
        #pragma unroll
        for (int r = 0; r < 16; r++)
            obuf[wid][dt][r][lane] = accO[dt][r];
    stat[0][wid][lane] = mrun;
    stat[1][wid][lane] = lrun;
    __syncthreads();

    float m0 = stat[0][0][lane], m1 = stat[0][1][lane];
    float m2 = stat[0][2][lane], m3 = stat[0][3][lane];
    float m = fmaxf(fmaxf(m0, m1), fmaxf(m2, m3));
    float f0 = exp2f((m0 - m) * cexp), f1 = exp2f((m1 - m) * cexp);
    float f2 = exp2f((m2 - m) * cexp), f3 = exp2f((m3 - m) * cexp);
    float lsum = f0 * stat[1][0][lane] + f1 * stat[1][1][lane]
               + f2 * stat[1][2][lane] + f3 * stat[1][3][lane];
    float linv = 1.0f / lsum;

    float o[16];
    #pragma unroll
    for (int r = 0; r < 16; r++)
        o[r] = (f0 * obuf[0][wid][r][lane] + f1 * obuf[1][wid][r][lane]
              + f2 * obuf[2][wid][r][lane] + f3 * obuf[3][wid][r][lane]) * linv;

    // wave wid owns output cols wid*32..+32; col = wid*32 + 8a + 4hi + e
    float* orow = out + ((size_t)b * 4096 + qt0 + lo) * 128 + wid * 32 + 4 * hi;
    #pragma unroll
    for (int a = 0; a < 4; a++) {
        float4 vv;
        vv.x = o[4 * a + 0]; vv.y = o[4 * a + 1];
        vv.z = o[4 * a + 2]; vv.w = o[4 * a + 3];
        *(float4*)(orow + 8 * a) = vv;
    }
}

// ---------------------------------------------------------------------------
extern "C" void kernel_launch(void* const* d_in, const int* in_sizes, int n_in,
                              void* d_out, int out_size, void* d_ws, size_t ws_size,
                              hipStream_t stream) {
    const float* x  = (const float*)d_in[0];
    const float* Wq = (const float*)d_in[1];
    const float* Wk = (const float*)d_in[2];
    const float* Wv = (const float*)d_in[3];
    float* out = (float*)d_out;
    char* ws = (char*)d_ws;

    ushort_t* q  = (ushort_t*)(ws);               // 4 MB  q_blk
    ushort_t* kb = (ushort_t*)(ws + (4u << 20));  // 4 MB  k_blk
    ushort_t* vb = (ushort_t*)(ws + (8u << 20));  // 4 MB  v_blk
    ushort_t* WT = (ushort_t*)(ws + (12u << 20)); // 1.5MB WT bf16 [384][2048]

    transpose_w<<<dim3(96), dim3(256), 0, stream>>>(Wq, Wk, Wv, WT);
    proj_kernel<<<dim3(512), dim3(256), 0, stream>>>(x, WT, q, kb, vb);
    attn_kernel<<<dim3(512), dim3(256), 0, stream>>>(q, kb, vb, out);
}

// Round 10
// 98.079 us; speedup vs baseline: 1.9845x; 1.9845x over previous
//
#include <hip/hip_runtime.h>
#include <hip/hip_bf16.h>
#include <stdint.h>

typedef unsigned short ushort_t;
typedef short v8s __attribute__((ext_vector_type(8)));
typedef float f32x4 __attribute__((ext_vector_type(4)));
typedef float f32x16 __attribute__((ext_vector_type(16)));

#define MFMA16(a, b, c) __builtin_amdgcn_mfma_f32_16x16x32_bf16(a, b, c, 0, 0, 0)
#define MFMA32(a, b, c) __builtin_amdgcn_mfma_f32_32x32x16_bf16(a, b, c, 0, 0, 0)

typedef __attribute__((address_space(1))) void gvoid;
typedef __attribute__((address_space(3))) void svoid;

__device__ __forceinline__ void gld16(const void* g, void* s) {
    __builtin_amdgcn_global_load_lds((gvoid*)g, (svoid*)s, 16, 0, 0);
}

__device__ __forceinline__ ushort_t f2bf(float f) {
    union { __hip_bfloat16 b; ushort_t u; } c;
    c.b = __float2bfloat16(f);
    return c.u;
}

__device__ __forceinline__ unsigned f2bf2(float a, float b) {
    union { __hip_bfloat162 b2; unsigned u; } c;
    c.b2 = __float22bfloat162_rn(make_float2(a, b));
    return c.u;
}

// ---------------------------------------------------------------------------
// Kernel 1: transpose W [2048][128] f32 -> WT [384][2048] bf16 (q|k|v rows)
// ---------------------------------------------------------------------------
__global__ void transpose_w(const float* __restrict__ Wq, const float* __restrict__ Wk,
                            const float* __restrict__ Wv, ushort_t* __restrict__ WT) {
    __shared__ float tile[64][132];
    int bid = blockIdx.x;            // 96 = 3 weights x 32 k-blocks
    int w = bid >> 5;
    int k0 = (bid & 31) << 6;
    const float* W = (w == 0) ? Wq : ((w == 1) ? Wk : Wv);
    int tid = threadIdx.x;
    #pragma unroll
    for (int i = 0; i < 8; i++) {
        int row = i * 8 + (tid >> 5);
        int col = (tid & 31) * 4;
        float4 v = *(const float4*)(W + (size_t)(k0 + row) * 128 + col);
        tile[row][col] = v.x; tile[row][col + 1] = v.y;
        tile[row][col + 2] = v.z; tile[row][col + 3] = v.w;
    }
    __syncthreads();
    int n = tid >> 1, kh = (tid & 1) * 32;
    ushort_t* dst = WT + ((size_t)(w * 128 + n)) * 2048 + k0 + kh;
    #pragma unroll
    for (int j = 0; j < 32; j += 4) {
        union { ushort_t u[4]; uint2 v2; } pk;
        #pragma unroll
        for (int e = 0; e < 4; e++) pk.u[e] = f2bf(tile[kh + j + e][n]);
        *(uint2*)(dst + j) = pk.v2;
    }
}

// ---------------------------------------------------------------------------
// Kernel 2: fused QKV projection v10 (= R8 + COALESCED x loads).
// grid 768 = 8 XCD x 32 mtiles x 3 ng; block = 64m x 128n (ng -> q/k/v),
// BK=64, 32 iters, 4 waves (2wr x 2wc), wave tile 32x64 (16 MFMA16/iter).
// A: x loaded COALESCED (lane i of 16 covers 16B of one row's 256B k-slice;
//    4 rows per instruction = 16 cache lines, was 64) 2-iters-ahead in regs
//    -> cvt_pk -> 8B ds_write into swizzled bf16 A (read path as R8, 0 confl).
// B: gld16 1 tile ahead, pre-swizzled source. LDS 48 KB dbuf -> 3 blocks/CU.
// Counted vmcnt(4) at the single per-iter barrier (x loads stay in flight).
// Blocked output layouts (per batch 524288 elems):
//   q_blk/k_blk: (t>>5)*4096 + (d>>4)*512 + ((d>>3)&1)*256 + (t&31)*8 + (d&7)
//   v_blk:       (t>>4)*2048 + (d>>5)*512 + ((t>>3)&1)*256 + (d&31)*8 + (t&7)
// ---------------------------------------------------------------------------
#define PJ_XLOAD(S, IT)                                                       \
    {                                                                         \
        _Pragma("unroll")                                                     \
        for (int i = 0; i < 4; i++)                                           \
            S[i] = *(const f32x4*)(xsrc[i] + (size_t)(IT) * 256);             \
    }

#define PJ_CVT_WRITE(RS, PAR)                                                 \
    {                                                                         \
        _Pragma("unroll")                                                     \
        for (int i = 0; i < 4; i++) {                                         \
            uint2 p;                                                          \
            p.x = f2bf2(RS[i][0], RS[i][1]);                                  \
            p.y = f2bf2(RS[i][2], RS[i][3]);                                  \
            *(uint2*)((char*)abuf + (PAR) * 8192 + awb[i]) = p;               \
        }                                                                     \
    }

#define PJ_STEP(PAR, IT, RLOAD, RCVT, DOX, DOB)                               \
    {                                                                         \
        if (DOB) {                                                            \
            _Pragma("unroll")                                                 \
            for (int i = 0; i < 4; i++)                                       \
                gld16(bsrc[i] + (size_t)((IT) + 1) * 128,                     \
                      (char*)bbuf + ((PAR) ^ 1) * 16384 + (4 * wid + i) * 1024); \
        }                                                                     \
        __builtin_amdgcn_sched_barrier(0);                                    \
        if (DOX) PJ_XLOAD(RLOAD, (IT) + 2);                                   \
        __builtin_amdgcn_sched_barrier(0);                                    \
        const char* ab = (const char*)abuf + (PAR) * 8192;                    \
        const char* bb = (const char*)bbuf + (PAR) * 16384;                   \
        _Pragma("unroll")                                                     \
        for (int kk = 0; kk < 2; kk++) {                                      \
            v8s af[2], bf[4];                                                 \
            _Pragma("unroll")                                                 \
            for (int m = 0; m < 2; m++) {                                     \
                int row = wr * 32 + m * 16 + lr;                              \
                af[m] = *(const v8s*)(ab + row * 128 +                        \
                         ((kk * 64 + lg * 16) ^ ((row & 7) << 4)));           \
            }                                                                 \
            _Pragma("unroll")                                                 \
            for (int n = 0; n < 4; n++) {                                     \
                int row = wc * 64 + n * 16 + lr;                              \
                bf[n] = *(const v8s*)(bb + row * 128 +                        \
                         ((kk * 64 + lg * 16) ^ ((row & 7) << 4)));           \
            }                                                                 \
            __builtin_amdgcn_s_setprio(1);                                    \
            _Pragma("unroll")                                                 \
            for (int m = 0; m < 2; m++)                                       \
                _Pragma("unroll")                                             \
                for (int n = 0; n < 4; n++)                                   \
                    acc[m][n] = MFMA16(af[m], bf[n], acc[m][n]);              \
            __builtin_amdgcn_s_setprio(0);                                    \
        }                                                                     \
        if (DOB) {                                                            \
            PJ_CVT_WRITE(RCVT, (PAR) ^ 1);                                    \
            if (DOX) { asm volatile("s_waitcnt vmcnt(4)" ::: "memory"); }     \
            else     { asm volatile("s_waitcnt vmcnt(0)" ::: "memory"); }     \
            asm volatile("s_waitcnt lgkmcnt(0)" ::: "memory");                \
            __builtin_amdgcn_s_barrier();                                     \
        }                                                                     \
    }

__launch_bounds__(256, 3)
__global__ void proj_kernel(const float* __restrict__ x, const ushort_t* __restrict__ WT,
                            ushort_t* __restrict__ q, ushort_t* __restrict__ kb,
                            ushort_t* __restrict__ vb) {
    __shared__ ushort_t abuf[2][4096];    // [64 m][64 k] bf16, byte ^ ((row&7)<<4)
    __shared__ ushort_t bbuf[2][8192];    // [128 n][64 k] bf16, same swizzle

    int bid = blockIdx.x;
    int xcd = bid & 7, idx = bid >> 3;
    int mt_local = idx / 3, ng = idx - 3 * mt_local;
    int mtile = xcd * 32 + mt_local;
    size_t m0 = (size_t)mtile * 64;
    int c0 = ng * 128;
    int tid = threadIdx.x, lane = tid & 63, wid = tid >> 6;
    int lg = lane >> 4, lr = lane & 15;
    int wr = wid >> 1, wc = wid & 1;

    f32x4 acc[2][4];
    #pragma unroll
    for (int m = 0; m < 2; m++)
        #pragma unroll
        for (int n = 0; n < 4; n++) acc[m][n] = (f32x4){0.f, 0.f, 0.f, 0.f};

    // A loads (COALESCED): inst i covers rows 16wid+4i..+3; lanes 0-15 = one
    // row's 256B k-slice (16B/lane). cvt -> 8B ds_write at swizzled awb[i].
    const char* xsrc[4];
    int awb[4];
    #pragma unroll
    for (int i = 0; i < 4; i++) {
        int row = 16 * wid + 4 * i + (lane >> 4);
        xsrc[i] = (const char*)x + (m0 + row) * 8192 + (lane & 15) * 16;
        awb[i] = row * 128 + (((lane & 15) * 8) ^ ((row & 7) << 4));
    }

    // B stage: 16 segs of 1KB; wave stages segs 4wid..4wid+3 (pre-swizzled).
    const char* bsrc[4];
    #pragma unroll
    for (int i = 0; i < 4; i++) {
        int row = 8 * (4 * wid + i) + (lane >> 3);
        int col = ((lane & 7) * 16) ^ ((row & 7) << 4);
        bsrc[i] = (const char*)WT + (size_t)(c0 + row) * 4096 + col;
    }

    f32x4 xs0[4], xs1[4];
    // ---- prologue: B(0)->buf0, x(0)->xs0, x(1)->xs1, cvt A(0)->abuf0 ----
    #pragma unroll
    for (int i = 0; i < 4; i++)
        gld16(bsrc[i], (char*)bbuf + (4 * wid + i) * 1024);
    PJ_XLOAD(xs0, 0);
    PJ_XLOAD(xs1, 1);
    PJ_CVT_WRITE(xs0, 0);
    asm volatile("s_waitcnt vmcnt(0)" ::: "memory");
    asm volatile("s_waitcnt lgkmcnt(0)" ::: "memory");
    __builtin_amdgcn_s_barrier();

    // steady state: step it reads buf[it&1]; x(n) lives in xs[n&1]
    for (int it = 0; it < 30; it += 2) {
        PJ_STEP(0, it,     xs0, xs1, 1, 1);
        PJ_STEP(1, it + 1, xs1, xs0, 1, 1);
    }
    PJ_STEP(0, 30, xs0, xs1, 0, 1);   // B(31)->buf1, cvt x(31)=xs1, vmcnt(0)
    PJ_STEP(1, 31, xs1, xs0, 0, 0);   // compute only

    // epilogue: D-frag lane holds row = 4*lg+e, col = lr within each 16x16 tile
    #pragma unroll
    for (int m = 0; m < 2; m++) {
        #pragma unroll
        for (int e = 0; e < 4; e++) {
            size_t row = m0 + (size_t)(wr * 32 + m * 16 + 4 * lg + e);
            int t = (int)(row & 4095);
            size_t base = (row >> 12) * 524288;
            #pragma unroll
            for (int n = 0; n < 4; n++) {
                int d = (wc * 64 + n * 16 + lr) & 127;
                ushort_t val = f2bf(acc[m][n][e]);
                if (ng == 0)
                    q[base + (size_t)(t >> 5) * 4096 + (d >> 4) * 512 + ((d >> 3) & 1) * 256 + (t & 31) * 8 + (d & 7)] = val;
                else if (ng == 1)
                    kb[base + (size_t)(t >> 5) * 4096 + (d >> 4) * 512 + ((d >> 3) & 1) * 256 + (t & 31) * 8 + (d & 7)] = val;
                else
                    vb[base + (size_t)(t >> 4) * 2048 + (d >> 5) * 512 + ((t >> 3) & 1) * 256 + (d & 31) * 8 + (t & 7)] = val;
            }
        }
    }
}

// ---------------------------------------------------------------------------
// Kernel 3: causal flash attention (UNCHANGED — ~19 µs, ~900 TF effective).
// 32x32 MFMA, swapped QK^T (S^T = K·Q^T), O^T = V^T·P^T. 512 blocks x 4
// waves; waves split KV tiles mod 4, merge partials via LDS at the end.
// ---------------------------------------------------------------------------
__device__ __forceinline__ f32x16 zero16() {
    f32x16 z;
    #pragma unroll
    for (int i = 0; i < 16; i++) z[i] = 0.f;
    return z;
}

#define ATT_PVC(SV, BASE, VC, CNEXT)                                          \
    {                                                                         \
        unsigned a0 = f2bf2(SV[(BASE) + 0], SV[(BASE) + 1]);                  \
        unsigned a1 = f2bf2(SV[(BASE) + 2], SV[(BASE) + 3]);                  \
        unsigned b0 = f2bf2(SV[(BASE) + 4], SV[(BASE) + 5]);                  \
        unsigned b1 = f2bf2(SV[(BASE) + 6], SV[(BASE) + 7]);                  \
        unsigned snd0 = hi ? a0 : b0, snd1 = hi ? a1 : b1;                    \
        unsigned rcv0 = (unsigned)__shfl_xor((int)snd0, 32);                  \
        unsigned rcv1 = (unsigned)__shfl_xor((int)snd1, 32);                  \
        union { unsigned u[4]; v8s v; } pf;                                   \
        pf.u[0] = hi ? rcv0 : a0;                                             \
        pf.u[1] = hi ? rcv1 : a1;                                             \
        pf.u[2] = hi ? b0 : rcv0;                                             \
        pf.u[3] = hi ? b1 : rcv1;                                             \
        __builtin_amdgcn_s_setprio(1);                                        \
        _Pragma("unroll")                                                     \
        for (int dt = 0; dt < 4; dt++)                                        \
            accO[dt] = MFMA32(VC[dt], pf.v, accO[dt]);                        \
        __builtin_amdgcn_s_setprio(0);                                        \
        if ((CNEXT) >= 0) {                                                   \
            _Pragma("unroll")                                                 \
            for (int dt = 0; dt < 4; dt++)                                    \
                VC[dt] = *(const v8s*)(vg + (CNEXT) * 2048 + dt * 512);       \
        }                                                                     \
    }

__launch_bounds__(256, 2)
__global__ void attn_kernel(const ushort_t* __restrict__ q, const ushort_t* __restrict__ kb,
                            const ushort_t* __restrict__ vb, float* __restrict__ out) {
    __shared__ float obuf[4][4][16][64];   // [srcwave][dt][r][lane]  64 KB
    __shared__ float stat[2][4][64];       // m, l per wave per lane

    int bid = blockIdx.x;
    int xcd = bid & 7, rk = bid >> 3;
    int b = xcd >> 1;                       // batch pinned to XCD pair
    int g = rk * 2 + (xcd & 1);             // 0..127
    int qt = (g & 1) ? (g >> 1) : (127 - (g >> 1));   // alternate long/short
    int qt0 = qt * 32;
    int tid = threadIdx.x, lane = tid & 63, wid = tid >> 6;
    int hi = lane >> 5, lo = lane & 31;
    size_t bb = (size_t)b * 524288;
    int nt = (qt >> 1) + 1;
    const float cexp = 0.08838834764831845f * 1.4426950408889634f;  // scale*log2e

    // Q fragments (B-operand): lane holds Q[qt0+lo][ks*16+hi*8+j]
    v8s qf[8];
    {
        const ushort_t* qg = q + bb + (size_t)qt * 4096 + (size_t)lane * 8;
        #pragma unroll
        for (int ks = 0; ks < 8; ks++) qf[ks] = *(const v8s*)(qg + ks * 512);
    }

    f32x16 accO[4];
    #pragma unroll
    for (int dt = 0; dt < 4; dt++) accO[dt] = zero16();
    float mrun = -1e30f, lrun = 0.f;

    for (int t = wid; t < nt; t += 4) {
        const ushort_t* kg = kb + bb + (size_t)t * 8192 + (size_t)lane * 8;
        const ushort_t* vg = vb + bb + (size_t)t * 8192 + (size_t)lane * 8;

        // S^T = K·Q^T : two 32-kv subtiles, K-loop over d (8 steps of 16)
        f32x16 s0 = zero16(), s1 = zero16();
        __builtin_amdgcn_s_setprio(1);
        #pragma unroll
        for (int ks = 0; ks < 8; ks++) {
            v8s kf = *(const v8s*)(kg + ks * 512);
            s0 = MFMA32(kf, qf[ks], s0);
        }
        #pragma unroll
        for (int ks = 0; ks < 8; ks++) {
            v8s kf = *(const v8s*)(kg + 4096 + ks * 512);
            s1 = MFMA32(kf, qf[ks], s1);
        }
        __builtin_amdgcn_s_setprio(0);

        // V-frag rolling pair: c=0 and c=1 issued here, latency hidden by
        // the mask + softmax VALU below.
        v8s vA[4], vB[4];
        #pragma unroll
        for (int dt = 0; dt < 4; dt++) vA[dt] = *(const v8s*)(vg + dt * 512);
        #pragma unroll
        for (int dt = 0; dt < 4; dt++) vB[dt] = *(const v8s*)(vg + 2048 + dt * 512);

        // causal mask (diagonal tile only); S^T row index kv=(r&3)+8*(r>>2)+4*hi
        if (t == nt - 1) {
            int qrow = qt0 + lo;
            #pragma unroll
            for (int r = 0; r < 16; r++) {
                int kvb = t * 64 + (r & 3) + 8 * (r >> 2) + 4 * hi;
                if (kvb > qrow) s0[r] = -1e30f;
                if (kvb + 32 > qrow) s1[r] = -1e30f;
            }
        }

        // online softmax: lane owns q-row lo; only cross-lane op is xor-32
        float mx = s0[0];
        #pragma unroll
        for (int r = 1; r < 16; r++) mx = fmaxf(mx, s0[r]);
        #pragma unroll
        for (int r = 0; r < 16; r++) mx = fmaxf(mx, s1[r]);
        mx = fmaxf(mx, __shfl_xor(mx, 32));

        if (__any(mx > mrun + 62.7f)) {     // defer-max: skip rescale if growth < 8/cexp
            float mnew = fmaxf(mrun, mx);
            float fr = exp2f((mrun - mnew) * cexp);
            lrun *= fr;
            #pragma unroll
            for (int dt = 0; dt < 4; dt++)
                #pragma unroll
                for (int r = 0; r < 16; r++) accO[dt][r] *= fr;
            mrun = mnew;
        }
        float mc = mrun * cexp;
        float rs = 0.f;
        #pragma unroll
        for (int r = 0; r < 16; r++) { s0[r] = exp2f(fmaf(s0[r], cexp, -mc)); rs += s0[r]; }
        #pragma unroll
        for (int r = 0; r < 16; r++) { s1[r] = exp2f(fmaf(s1[r], cexp, -mc)); rs += s1[r]; }
        rs += __shfl_xor(rs, 32);
        lrun += rs;

        // PV: O^T += V^T·P^T ; P-frag assembled in-loop (1 shfl pair / chunk),
        // V-frags prefetched 2 chunks ahead into the just-consumed set.
        ATT_PVC(s0, 0, vA, 2);
        ATT_PVC(s0, 8, vB, 3);
        ATT_PVC(s1, 0, vA, -1);
        ATT_PVC(s1, 8, vB, -1);
    }

    // ---- merge the 4 waves' partial (m, l, O^T) states ----
    #pragma unroll
    for (int dt = 0; dt < 4; dt++)
        #pragma unroll
        for (int r = 0; r < 16; r++)
            obuf[wid][dt][r][lane] = accO[dt][r];
    stat[0][wid][lane] = mrun;
    stat[1][wid][lane] = lrun;
    __syncthreads();

    float m0 = stat[0][0][lane], m1 = stat[0][1][lane];
    float m2 = stat[0][2][lane], m3 = stat[0][3][lane];
    float m = fmaxf(fmaxf(m0, m1), fmaxf(m2, m3));
    float f0 = exp2f((m0 - m) * cexp), f1 = exp2f((m1 - m) * cexp);
    float f2 = exp2f((m2 - m) * cexp), f3 = exp2f((m3 - m) * cexp);
    float lsum = f0 * stat[1][0][lane] + f1 * stat[1][1][lane]
               + f2 * stat[1][2][lane] + f3 * stat[1][3][lane];
    float linv = 1.0f / lsum;

    float o[16];
    #pragma unroll
    for (int r = 0; r < 16; r++)
        o[r] = (f0 * obuf[0][wid][r][lane] + f1 * obuf[1][wid][r][lane]
              + f2 * obuf[2][wid][r][lane] + f3 * obuf[3][wid][r][lane]) * linv;

    // wave wid owns output cols wid*32..+32; col = wid*32 + 8a + 4hi + e
    float* orow = out + ((size_t)b * 4096 + qt0 + lo) * 128 + wid * 32 + 4 * hi;
    #pragma unroll
    for (int a = 0; a < 4; a++) {
        float4 vv;
        vv.x = o[4 * a + 0]; vv.y = o[4 * a + 1];
        vv.z = o[4 * a + 2]; vv.w = o[4 * a + 3];
        *(float4*)(orow + 8 * a) = vv;
    }
}

// ---------------------------------------------------------------------------
extern "C" void kernel_launch(void* const* d_in, const int* in_sizes, int n_in,
                              void* d_out, int out_size, void* d_ws, size_t ws_size,
                              hipStream_t stream) {
    const float* x  = (const float*)d_in[0];
    const float* Wq = (const float*)d_in[1];
    const float* Wk = (const float*)d_in[2];
    const float* Wv = (const float*)d_in[3];
    float* out = (float*)d_out;
    char* ws = (char*)d_ws;

    ushort_t* q  = (ushort_t*)(ws);               // 4 MB  q_blk
    ushort_t* kb = (ushort_t*)(ws + (4u << 20));  // 4 MB  k_blk
    ushort_t* vb = (ushort_t*)(ws + (8u << 20));  // 4 MB  v_blk
    ushort_t* WT = (ushort_t*)(ws + (12u << 20)); // 1.5MB WT bf16 [384][2048]

    transpose_w<<<dim3(96), dim3(256), 0, stream>>>(Wq, Wk, Wv, WT);
    proj_kernel<<<dim3(768), dim3(256), 0, stream>>>(x, WT, q, kb, vb);
    attn_kernel<<<dim3(512), dim3(256), 0, stream>>>(q, kb, vb, out);
}

// Round 11
// 95.542 us; speedup vs baseline: 2.0372x; 1.0265x over previous
//
#include <hip/hip_runtime.h>
#include <hip/hip_bf16.h>
#include <stdint.h>

typedef unsigned short ushort_t;
typedef short v8s __attribute__((ext_vector_type(8)));
typedef float f32x4 __attribute__((ext_vector_type(4)));
typedef float f32x16 __attribute__((ext_vector_type(16)));

#define MFMA16(a, b, c) __builtin_amdgcn_mfma_f32_16x16x32_bf16(a, b, c, 0, 0, 0)
#define MFMA32(a, b, c) __builtin_amdgcn_mfma_f32_32x32x16_bf16(a, b, c, 0, 0, 0)

typedef __attribute__((address_space(1))) void gvoid;
typedef __attribute__((address_space(3))) void svoid;

__device__ __forceinline__ void gld16(const void* g, void* s) {
    __builtin_amdgcn_global_load_lds((gvoid*)g, (svoid*)s, 16, 0, 0);
}

__device__ __forceinline__ ushort_t f2bf(float f) {
    union { __hip_bfloat16 b; ushort_t u; } c;
    c.b = __float2bfloat16(f);
    return c.u;
}

__device__ __forceinline__ unsigned f2bf2(float a, float b) {
    union { __hip_bfloat162 b2; unsigned u; } c;
    c.b2 = __float22bfloat162_rn(make_float2(a, b));
    return c.u;
}

// ---------------------------------------------------------------------------
// Kernel 1: transpose W [2048][128] f32 -> WT [384][2048] bf16 (q|k|v rows)
// ---------------------------------------------------------------------------
__global__ void transpose_w(const float* __restrict__ Wq, const float* __restrict__ Wk,
                            const float* __restrict__ Wv, ushort_t* __restrict__ WT) {
    __shared__ float tile[64][132];
    int bid = blockIdx.x;            // 96 = 3 weights x 32 k-blocks
    int w = bid >> 5;
    int k0 = (bid & 31) << 6;
    const float* W = (w == 0) ? Wq : ((w == 1) ? Wk : Wv);
    int tid = threadIdx.x;
    #pragma unroll
    for (int i = 0; i < 8; i++) {
        int row = i * 8 + (tid >> 5);
        int col = (tid & 31) * 4;
        float4 v = *(const float4*)(W + (size_t)(k0 + row) * 128 + col);
        tile[row][col] = v.x; tile[row][col + 1] = v.y;
        tile[row][col + 2] = v.z; tile[row][col + 3] = v.w;
    }
    __syncthreads();
    int n = tid >> 1, kh = (tid & 1) * 32;
    ushort_t* dst = WT + ((size_t)(w * 128 + n)) * 2048 + k0 + kh;
    #pragma unroll
    for (int j = 0; j < 32; j += 4) {
        union { ushort_t u[4]; uint2 v2; } pk;
        #pragma unroll
        for (int e = 0; e < 4; e++) pk.u[e] = f2bf(tile[kh + j + e][n]);
        *(uint2*)(dst + j) = pk.v2;
    }
}

// ---------------------------------------------------------------------------
// Kernel 2: fused QKV projection v11 (= R10 + L1-sharing trio mapping).
// grid 768 = 8 XCD x (32 mtiles x 3 ng). NEW MAPPING: within an XCD,
// k = bid>>3; mt_local = k & 31, ng = k >> 5. Under sequential CU fill,
// CU_j hosts its XCD's k = j, j+32, j+64 -> SAME mtile, ng = 0,1,2:
// the 3 co-resident blocks stage the SAME 16 KB x panel each iteration in
// lockstep -> 2 of 3 x-stagings hit L1 -> per-CU L2 demand 96->64 KB/slot.
// (Theory: proj is per-CU L2-BW-bound at ~56-60 B/cy; R10 measured 2000
// cy/slot ~= 96 KB / 56 B/cy.)
// Everything else identical to R10: block = 64m x 128n, BK=64, 32 iters,
// 4 waves (2wr x 2wc), A coalesced f32 reg loads 2-ahead -> cvt_pk -> 8B
// ds_write (swizzled, 0 conflicts); B gld16 1-ahead pre-swizzled; LDS 48 KB
// dbuf, 3 blocks/CU; counted vmcnt(4) at the single per-iter barrier.
// Blocked output layouts (per batch 524288 elems):
//   q_blk/k_blk: (t>>5)*4096 + (d>>4)*512 + ((d>>3)&1)*256 + (t&31)*8 + (d&7)
//   v_blk:       (t>>4)*2048 + (d>>5)*512 + ((t>>3)&1)*256 + (d&31)*8 + (t&7)
// ---------------------------------------------------------------------------
#define PJ_XLOAD(S, IT)                                                       \
    {                                                                         \
        _Pragma("unroll")                                                     \
        for (int i = 0; i < 4; i++)                                           \
            S[i] = *(const f32x4*)(xsrc[i] + (size_t)(IT) * 256);             \
    }

#define PJ_CVT_WRITE(RS, PAR)                                                 \
    {                                                                         \
        _Pragma("unroll")                                                     \
        for (int i = 0; i < 4; i++) {                                         \
            uint2 p;                                                          \
            p.x = f2bf2(RS[i][0], RS[i][1]);                                  \
            p.y = f2bf2(RS[i][2], RS[i][3]);                                  \
            *(uint2*)((char*)abuf + (PAR) * 8192 + awb[i]) = p;               \
        }                                                                     \
    }

#define PJ_STEP(PAR, IT, RLOAD, RCVT, DOX, DOB)                               \
    {                                                                         \
        if (DOB) {                                                            \
            _Pragma("unroll")                                                 \
            for (int i = 0; i < 4; i++)                                       \
                gld16(bsrc[i] + (size_t)((IT) + 1) * 128,                     \
                      (char*)bbuf + ((PAR) ^ 1) * 16384 + (4 * wid + i) * 1024); \
        }                                                                     \
        __builtin_amdgcn_sched_barrier(0);                                    \
        if (DOX) PJ_XLOAD(RLOAD, (IT) + 2);                                   \
        __builtin_amdgcn_sched_barrier(0);                                    \
        const char* ab = (const char*)abuf + (PAR) * 8192;                    \
        const char* bb = (const char*)bbuf + (PAR) * 16384;                   \
        _Pragma("unroll")                                                     \
        for (int kk = 0; kk < 2; kk++) {                                      \
            v8s af[2], bf[4];                                                 \
            _Pragma("unroll")                                                 \
            for (int m = 0; m < 2; m++) {                                     \
                int row = wr * 32 + m * 16 + lr;                              \
                af[m] = *(const v8s*)(ab + row * 128 +                        \
                         ((kk * 64 + lg * 16) ^ ((row & 7) << 4)));           \
            }                                                                 \
            _Pragma("unroll")                                                 \
            for (int n = 0; n < 4; n++) {                                     \
                int row = wc * 64 + n * 16 + lr;                              \
                bf[n] = *(const v8s*)(bb + row * 128 +                        \
                         ((kk * 64 + lg * 16) ^ ((row & 7) << 4)));           \
            }                                                                 \
            __builtin_amdgcn_s_setprio(1);                                    \
            _Pragma("unroll")                                                 \
            for (int m = 0; m < 2; m++)                                       \
                _Pragma("unroll")                                             \
                for (int n = 0; n < 4; n++)                                   \
                    acc[m][n] = MFMA16(af[m], bf[n], acc[m][n]);              \
            __builtin_amdgcn_s_setprio(0);                                    \
        }                                                                     \
        if (DOB) {                                                            \
            PJ_CVT_WRITE(RCVT, (PAR) ^ 1);                                    \
            if (DOX) { asm volatile("s_waitcnt vmcnt(4)" ::: "memory"); }     \
            else     { asm volatile("s_waitcnt vmcnt(0)" ::: "memory"); }     \
            asm volatile("s_waitcnt lgkmcnt(0)" ::: "memory");                \
            __builtin_amdgcn_s_barrier();                                     \
        }                                                                     \
    }

__launch_bounds__(256, 3)
__global__ void proj_kernel(const float* __restrict__ x, const ushort_t* __restrict__ WT,
                            ushort_t* __restrict__ q, ushort_t* __restrict__ kb,
                            ushort_t* __restrict__ vb) {
    __shared__ ushort_t abuf[2][4096];    // [64 m][64 k] bf16, byte ^ ((row&7)<<4)
    __shared__ ushort_t bbuf[2][8192];    // [128 n][64 k] bf16, same swizzle

    int bid = blockIdx.x;
    int xcd = bid & 7, k = bid >> 3;
    int mt_local = k & 31, ng = k >> 5;   // L1-sharing trio: same mtile, ng 0/1/2
    int mtile = xcd * 32 + mt_local;
    size_t m0 = (size_t)mtile * 64;
    int c0 = ng * 128;
    int tid = threadIdx.x, lane = tid & 63, wid = tid >> 6;
    int lg = lane >> 4, lr = lane & 15;
    int wr = wid >> 1, wc = wid & 1;

    f32x4 acc[2][4];
    #pragma unroll
    for (int m = 0; m < 2; m++)
        #pragma unroll
        for (int n = 0; n < 4; n++) acc[m][n] = (f32x4){0.f, 0.f, 0.f, 0.f};

    // A loads (COALESCED): inst i covers rows 16wid+4i..+3; lanes 0-15 = one
    // row's 256B k-slice (16B/lane). cvt -> 8B ds_write at swizzled awb[i].
    const char* xsrc[4];
    int awb[4];
    #pragma unroll
    for (int i = 0; i < 4; i++) {
        int row = 16 * wid + 4 * i + (lane >> 4);
        xsrc[i] = (const char*)x + (m0 + row) * 8192 + (lane & 15) * 16;
        awb[i] = row * 128 + (((lane & 15) * 8) ^ ((row & 7) << 4));
    }

    // B stage: 16 segs of 1KB; wave stages segs 4wid..4wid+3 (pre-swizzled).
    const char* bsrc[4];
    #pragma unroll
    for (int i = 0; i < 4; i++) {
        int row = 8 * (4 * wid + i) + (lane >> 3);
        int col = ((lane & 7) * 16) ^ ((row & 7) << 4);
        bsrc[i] = (const char*)WT + (size_t)(c0 + row) * 4096 + col;
    }

    f32x4 xs0[4], xs1[4];
    // ---- prologue: B(0)->buf0, x(0)->xs0, x(1)->xs1, cvt A(0)->abuf0 ----
    #pragma unroll
    for (int i = 0; i < 4; i++)
        gld16(bsrc[i], (char*)bbuf + (4 * wid + i) * 1024);
    PJ_XLOAD(xs0, 0);
    PJ_XLOAD(xs1, 1);
    PJ_CVT_WRITE(xs0, 0);
    asm volatile("s_waitcnt vmcnt(0)" ::: "memory");
    asm volatile("s_waitcnt lgkmcnt(0)" ::: "memory");
    __builtin_amdgcn_s_barrier();

    // steady state: step it reads buf[it&1]; x(n) lives in xs[n&1]
    for (int it = 0; it < 30; it += 2) {
        PJ_STEP(0, it,     xs0, xs1, 1, 1);
        PJ_STEP(1, it + 1, xs1, xs0, 1, 1);
    }
    PJ_STEP(0, 30, xs0, xs1, 0, 1);   // B(31)->buf1, cvt x(31)=xs1, vmcnt(0)
    PJ_STEP(1, 31, xs1, xs0, 0, 0);   // compute only

    // epilogue: D-frag lane holds row = 4*lg+e, col = lr within each 16x16 tile
    #pragma unroll
    for (int m = 0; m < 2; m++) {
        #pragma unroll
        for (int e = 0; e < 4; e++) {
            size_t row = m0 + (size_t)(wr * 32 + m * 16 + 4 * lg + e);
            int t = (int)(row & 4095);
            size_t base = (row >> 12) * 524288;
            #pragma unroll
            for (int n = 0; n < 4; n++) {
                int d = (wc * 64 + n * 16 + lr) & 127;
                ushort_t val = f2bf(acc[m][n][e]);
                if (ng == 0)
                    q[base + (size_t)(t >> 5) * 4096 + (d >> 4) * 512 + ((d >> 3) & 1) * 256 + (t & 31) * 8 + (d & 7)] = val;
                else if (ng == 1)
                    kb[base + (size_t)(t >> 5) * 4096 + (d >> 4) * 512 + ((d >> 3) & 1) * 256 + (t & 31) * 8 + (d & 7)] = val;
                else
                    vb[base + (size_t)(t >> 4) * 2048 + (d >> 5) * 512 + ((t >> 3) & 1) * 256 + (d & 31) * 8 + (t & 7)] = val;
            }
        }
    }
}

// ---------------------------------------------------------------------------
// Kernel 3: causal flash attention (UNCHANGED — ~17-19 µs, ~900 TF effective).
// 32x32 MFMA, swapped QK^T (S^T = K·Q^T), O^T = V^T·P^T. 512 blocks x 4
// waves; waves split KV tiles mod 4, merge partials via LDS at the end.
// ---------------------------------------------------------------------------
__device__ __forceinline__ f32x16 zero16() {
    f32x16 z;
    #pragma unroll
    for (int i = 0; i < 16; i++) z[i] = 0.f;
    return z;
}

#define ATT_PVC(SV, BASE, VC, CNEXT)                                          \
    {                                                                         \
        unsigned a0 = f2bf2(SV[(BASE) + 0], SV[(BASE) + 1]);                  \
        unsigned a1 = f2bf2(SV[(BASE) + 2], SV[(BASE) + 3]);                  \
        unsigned b0 = f2bf2(SV[(BASE) + 4], SV[(BASE) + 5]);                  \
        unsigned b1 = f2bf2(SV[(BASE) + 6], SV[(BASE) + 7]);                  \
        unsigned snd0 = hi ? a0 : b0, snd1 = hi ? a1 : b1;                    \
        unsigned rcv0 = (unsigned)__shfl_xor((int)snd0, 32);                  \
        unsigned rcv1 = (unsigned)__shfl_xor((int)snd1, 32);                  \
        union { unsigned u[4]; v8s v; } pf;                                   \
        pf.u[0] = hi ? rcv0 : a0;                                             \
        pf.u[1] = hi ? rcv1 : a1;                                             \
        pf.u[2] = hi ? b0 : rcv0;                                             \
        pf.u[3] = hi ? b1 : rcv1;                                             \
        __builtin_amdgcn_s_setprio(1);                                        \
        _Pragma("unroll")                                                     \
        for (int dt = 0; dt < 4; dt++)                                        \
            accO[dt] = MFMA32(VC[dt], pf.v, accO[dt]);                        \
        __builtin_amdgcn_s_setprio(0);                                        \
        if ((CNEXT) >= 0) {                                                   \
            _Pragma("unroll")                                                 \
            for (int dt = 0; dt < 4; dt++)                                    \
                VC[dt] = *(const v8s*)(vg + (CNEXT) * 2048 + dt * 512);       \
        }                                                                     \
    }

__launch_bounds__(256, 2)
__global__ void attn_kernel(const ushort_t* __restrict__ q, const ushort_t* __restrict__ kb,
                            const ushort_t* __restrict__ vb, float* __restrict__ out) {
    __shared__ float obuf[4][4][16][64];   // [srcwave][dt][r][lane]  64 KB
    __shared__ float stat[2][4][64];       // m, l per wave per lane

    int bid = blockIdx.x;
    int xcd = bid & 7, rk = bid >> 3;
    int b = xcd >> 1;                       // batch pinned to XCD pair
    int g = rk * 2 + (xcd & 1);             // 0..127
    int qt = (g & 1) ? (g >> 1) : (127 - (g >> 1));   // alternate long/short
    int qt0 = qt * 32;
    int tid = threadIdx.x, lane = tid & 63, wid = tid >> 6;
    int hi = lane >> 5, lo = lane & 31;
    size_t bb = (size_t)b * 524288;
    int nt = (qt >> 1) + 1;
    const float cexp = 0.08838834764831845f * 1.4426950408889634f;  // scale*log2e

    // Q fragments (B-operand): lane holds Q[qt0+lo][ks*16+hi*8+j]
    v8s qf[8];
    {
        const ushort_t* qg = q + bb + (size_t)qt * 4096 + (size_t)lane * 8;
        #pragma unroll
        for (int ks = 0; ks < 8; ks++) qf[ks] = *(const v8s*)(qg + ks * 512);
    }

    f32x16 accO[4];
    #pragma unroll
    for (int dt = 0; dt < 4; dt++) accO[dt] = zero16();
    float mrun = -1e30f, lrun = 0.f;

    for (int t = wid; t < nt; t += 4) {
        const ushort_t* kg = kb + bb + (size_t)t * 8192 + (size_t)lane * 8;
        const ushort_t* vg = vb + bb + (size_t)t * 8192 + (size_t)lane * 8;

        // S^T = K·Q^T : two 32-kv subtiles, K-loop over d (8 steps of 16)
        f32x16 s0 = zero16(), s1 = zero16();
        __builtin_amdgcn_s_setprio(1);
        #pragma unroll
        for (int ks = 0; ks < 8; ks++) {
            v8s kf = *(const v8s*)(kg + ks * 512);
            s0 = MFMA32(kf, qf[ks], s0);
        }
        #pragma unroll
        for (int ks = 0; ks < 8; ks++) {
            v8s kf = *(const v8s*)(kg + 4096 + ks * 512);
            s1 = MFMA32(kf, qf[ks], s1);
        }
        __builtin_amdgcn_s_setprio(0);

        // V-frag rolling pair: c=0 and c=1 issued here, latency hidden by
        // the mask + softmax VALU below.
        v8s vA[4], vB[4];
        #pragma unroll
        for (int dt = 0; dt < 4; dt++) vA[dt] = *(const v8s*)(vg + dt * 512);
        #pragma unroll
        for (int dt = 0; dt < 4; dt++) vB[dt] = *(const v8s*)(vg + 2048 + dt * 512);

        // causal mask (diagonal tile only); S^T row index kv=(r&3)+8*(r>>2)+4*hi
        if (t == nt - 1) {
            int qrow = qt0 + lo;
            #pragma unroll
            for (int r = 0; r < 16; r++) {
                int kvb = t * 64 + (r & 3) + 8 * (r >> 2) + 4 * hi;
                if (kvb > qrow) s0[r] = -1e30f;
                if (kvb + 32 > qrow) s1[r] = -1e30f;
            }
        }

        // online softmax: lane owns q-row lo; only cross-lane op is xor-32
        float mx = s0[0];
        #pragma unroll
        for (int r = 1; r < 16; r++) mx = fmaxf(mx, s0[r]);
        #pragma unroll
        for (int r = 0; r < 16; r++) mx = fmaxf(mx, s1[r]);
        mx = fmaxf(mx, __shfl_xor(mx, 32));

        if (__any(mx > mrun + 62.7f)) {     // defer-max: skip rescale if growth < 8/cexp
            float mnew = fmaxf(mrun, mx);
            float fr = exp2f((mrun - mnew) * cexp);
            lrun *= fr;
            #pragma unroll
            for (int dt = 0; dt < 4; dt++)
                #pragma unroll
                for (int r = 0; r < 16; r++) accO[dt][r] *= fr;
            mrun = mnew;
        }
        float mc = mrun * cexp;
        float rs = 0.f;
        #pragma unroll
        for (int r = 0; r < 16; r++) { s0[r] = exp2f(fmaf(s0[r], cexp, -mc)); rs += s0[r]; }
        #pragma unroll
        for (int r = 0; r < 16; r++) { s1[r] = exp2f(fmaf(s1[r], cexp, -mc)); rs += s1[r]; }
        rs += __shfl_xor(rs, 32);
        lrun += rs;

        // PV: O^T += V^T·P^T ; P-frag assembled in-loop (1 shfl pair / chunk),
        // V-frags prefetched 2 chunks ahead into the just-consumed set.
        ATT_PVC(s0, 0, vA, 2);
        ATT_PVC(s0, 8, vB, 3);
        ATT_PVC(s1, 0, vA, -1);
        ATT_PVC(s1, 8, vB, -1);
    }

    // ---- merge the 4 waves' partial (m, l, O^T) states ----
    #pragma unroll
    for (int dt = 0; dt < 4; dt++)
        #pragma unroll
        for (int r = 0; r < 16; r++)
            obuf[wid][dt][r][lane] = accO[dt][r];
    stat[0][wid][lane] = mrun;
    stat[1][wid][lane] = lrun;
    __syncthreads();

    float m0 = stat[0][0][lane], m1 = stat[0][1][lane];
    float m2 = stat[0][2][lane], m3 = stat[0][3][lane];
    float m = fmaxf(fmaxf(m0, m1), fmaxf(m2, m3));
    float f0 = exp2f((m0 - m) * cexp), f1 = exp2f((m1 - m) * cexp);
    float f2 = exp2f((m2 - m) * cexp), f3 = exp2f((m3 - m) * cexp);
    float lsum = f0 * stat[1][0][lane] + f1 * stat[1][1][lane]
               + f2 * stat[1][2][lane] + f3 * stat[1][3][lane];
    float linv = 1.0f / lsum;

    float o[16];
    #pragma unroll
    for (int r = 0; r < 16; r++)
        o[r] = (f0 * obuf[0][wid][r][lane] + f1 * obuf[1][wid][r][lane]
              + f2 * obuf[2][wid][r][lane] + f3 * obuf[3][wid][r][lane]) * linv;

    // wave wid owns output cols wid*32..+32; col = wid*32 + 8a + 4hi + e
    float* orow = out + ((size_t)b * 4096 + qt0 + lo) * 128 + wid * 32 + 4 * hi;
    #pragma unroll
    for (int a = 0; a < 4; a++) {
        float4 vv;
        vv.x = o[4 * a + 0]; vv.y = o[4 * a + 1];
        vv.z = o[4 * a + 2]; vv.w = o[4 * a + 3];
        *(float4*)(orow + 8 * a) = vv;
    }
}

// ---------------------------------------------------------------------------
extern "C" void kernel_launch(void* const* d_in, const int* in_sizes, int n_in,
                              void* d_out, int out_size, void* d_ws, size_t ws_size,
                              hipStream_t stream) {
    const float* x  = (const float*)d_in[0];
    const float* Wq = (const float*)d_in[1];
    const float* Wk = (const float*)d_in[2];
    const float* Wv = (const float*)d_in[3];
    float* out = (float*)d_out;
    char* ws = (char*)d_ws;

    ushort_t* q  = (ushort_t*)(ws);               // 4 MB  q_blk
    ushort_t* kb = (ushort_t*)(ws + (4u << 20));  // 4 MB  k_blk
    ushort_t* vb = (ushort_t*)(ws + (8u << 20));  // 4 MB  v_blk
    ushort_t* WT = (ushort_t*)(ws + (12u << 20)); // 1.5MB WT bf16 [384][2048]

    transpose_w<<<dim3(96), dim3(256), 0, stream>>>(Wq, Wk, Wv, WT);
    proj_kernel<<<dim3(768), dim3(256), 0, stream>>>(x, WT, q, kb, vb);
    attn_kernel<<<dim3(512), dim3(256), 0, stream>>>(q, kb, vb, out);
}